// Round 2
// baseline (237.771 us; speedup 1.0000x reference)
//
#include <hip/hip_runtime.h>
#include <math.h>

// x [B=256, T=4096, C=32] f32 -> out [B, 64, 64, 32] f32, PAA=64, GADF.
// One 1024-thread block per batch b (16 waves/CU): streaming pass fuses
// min/max + raw segment sums (PAA mean commutes with the affine rescale),
// then outer-product write phase from LDS.
#define BB   256
#define TT   4096
#define CC   32
#define PP   64      // paa_size
#define PSTR 36      // padded LDS row stride (floats)

__device__ __forceinline__ float4 f4min(float4 a, float4 b) {
    return make_float4(fminf(a.x,b.x), fminf(a.y,b.y), fminf(a.z,b.z), fminf(a.w,b.w));
}
__device__ __forceinline__ float4 f4max(float4 a, float4 b) {
    return make_float4(fmaxf(a.x,b.x), fmaxf(a.y,b.y), fmaxf(a.z,b.z), fmaxf(a.w,b.w));
}
__device__ __forceinline__ void f4add(float4& a, float4 v) {
    a.x += v.x; a.y += v.y; a.z += v.z; a.w += v.w;
}
__device__ __forceinline__ float4 shflxor4(float4 v, int m) {
    return make_float4(__shfl_xor(v.x, m), __shfl_xor(v.y, m),
                       __shfl_xor(v.z, m), __shfl_xor(v.w, m));
}

__global__ __launch_bounds__(1024) void gaf_kernel(const float* __restrict__ x,
                                                   float* __restrict__ out) {
    __shared__ float sp[PP * PSTR];        // p[64][36]
    __shared__ float sy[PP * PSTR];        // y[64][36]
    __shared__ float redmin[16 * CC];      // per-wave channel mins (16 waves)
    __shared__ float redmax[16 * CC];

    const int tid  = threadIdx.x;
    const int cg   = tid & 7;     // channel group: channels [4cg, 4cg+4)
    const int rb   = tid >> 3;    // 0..127: owns t in [rb*32, rb*32+32) = half of segment rb>>1
    const int wave = tid >> 6;    // 0..15
    const int lane = tid & 63;
    const int b    = blockIdx.x;

    // ---- Phase 1: single streaming pass — min/max + raw half-segment sums ----
    const float4* x4 = (const float4*)x + (size_t)b * (TT * CC / 4) + rb * 256 + cg;

    const float FBIG = 3.402823466e+38f;
    float4 mn = make_float4(FBIG, FBIG, FBIG, FBIG);
    float4 mx = make_float4(-FBIG, -FBIG, -FBIG, -FBIG);
    float4 acc = make_float4(0.f, 0.f, 0.f, 0.f);

    #pragma unroll 8
    for (int k = 0; k < 32; ++k) {
        float4 v = x4[k * 8];
        mn = f4min(mn, v); mx = f4max(mx, v); f4add(acc, v);
    }

    // combine half-segment sums: partner is rb^1 == lane^8 (same wave, same cg)
    float4 seg = acc;
    f4add(seg, shflxor4(acc, 8));          // full segment sum for s = rb>>1

    // reduce min/max across the 8 rb values in this wave sharing cg
    #pragma unroll
    for (int m = 8; m <= 32; m <<= 1) {
        mn = f4min(mn, shflxor4(mn, m));
        mx = f4max(mx, shflxor4(mx, m));
    }
    if (lane < 8) {                        // lane == cg, holds wave-reduced value
        *(float4*)&redmin[wave * CC + cg * 4] = mn;
        *(float4*)&redmax[wave * CC + cg * 4] = mx;
    }
    __syncthreads();

    float4 gmn = *(const float4*)&redmin[0 * CC + cg * 4];
    float4 gmx = *(const float4*)&redmax[0 * CC + cg * 4];
    #pragma unroll
    for (int w = 1; w < 16; ++w) {
        gmn = f4min(gmn, *(const float4*)&redmin[w * CC + cg * 4]);
        gmx = f4max(gmx, *(const float4*)&redmax[w * CC + cg * 4]);
    }

    if ((rb & 1) == 0) {
        const int s = rb >> 1;
        float4 inv;
        inv.x = 1.0f / (gmx.x - gmn.x);
        inv.y = 1.0f / (gmx.y - gmn.y);
        inv.z = 1.0f / (gmx.z - gmn.z);
        inv.w = 1.0f / (gmx.w - gmn.w);
        const float s64 = 1.0f / 64.0f;
        float4 p, y;
        p.x = (seg.x * s64 - gmn.x) * inv.x;  p.y = (seg.y * s64 - gmn.y) * inv.y;
        p.z = (seg.z * s64 - gmn.z) * inv.z;  p.w = (seg.w * s64 - gmn.w) * inv.w;
        y.x = sqrtf(fmaxf(1.f - p.x * p.x, 0.f));  y.y = sqrtf(fmaxf(1.f - p.y * p.y, 0.f));
        y.z = sqrtf(fmaxf(1.f - p.z * p.z, 0.f));  y.w = sqrtf(fmaxf(1.f - p.w * p.w, 0.f));
        *(float4*)&sp[s * PSTR + cg * 4] = p;
        *(float4*)&sy[s * PSTR + cg * 4] = y;
    }
    __syncthreads();

    // ---- Phase 2: out[b,i,j,c] = y_i*p_j - p_i*y_j ----
    // Thread owns one j column (hoisted), 32 i rows, 4 channels.
    const int j  = (tid >> 3) & 63;
    const int ih = tid >> 9;               // 0 or 1: i in [ih*32, ih*32+32)
    const float4 pj = *(const float4*)&sp[j * PSTR + cg * 4];
    const float4 yj = *(const float4*)&sy[j * PSTR + cg * 4];

    float4* o4 = (float4*)out + (size_t)b * (PP * PP * CC / 4);

    #pragma unroll 8
    for (int ii = 0; ii < 32; ++ii) {
        const int i = ih * 32 + ii;
        const float4 pi = *(const float4*)&sp[i * PSTR + cg * 4];
        const float4 yi = *(const float4*)&sy[i * PSTR + cg * 4];
        float4 r;
        r.x = yi.x * pj.x - pi.x * yj.x;  r.y = yi.y * pj.y - pi.y * yj.y;
        r.z = yi.z * pj.z - pi.z * yj.z;  r.w = yi.w * pj.w - pi.w * yj.w;
        o4[i * 512 + j * 8 + cg] = r;
    }
}

extern "C" void kernel_launch(void* const* d_in, const int* in_sizes, int n_in,
                              void* d_out, int out_size, void* d_ws, size_t ws_size,
                              hipStream_t stream) {
    const float* x = (const float*)d_in[0];
    float* out = (float*)d_out;
    gaf_kernel<<<BB, 1024, 0, stream>>>(x, out);
}

// Round 3
// 231.287 us; speedup vs baseline: 1.0280x; 1.0280x over previous
//
#include <hip/hip_runtime.h>
#include <math.h>

// x [B=256, T=4096, C=32] f32 -> out [B, 64, 64, 32] f32, PAA=64, GADF.
// One 1024-thread block (16 waves) per batch b.
// Phase 1: each wave streams a CONTIGUOUS 32 KB slab of x (1 KB per load
//   instruction, sequential) computing min/max + raw segment sums (PAA mean
//   commutes with the affine rescale).
// Phase 2: each wave writes a CONTIGUOUS 32 KB slab of out (i in [4w,4w+4)),
//   1 KB per store instruction, sequential. p_j/y_j hoisted to registers.
// Rationale: R1/R2 showed 2.4 TB/s effective regardless of occupancy with
// 128B-stride lockstep access; fillBuffer (sequential) hits 6.6 TB/s.
#define BB   256
#define TT   4096
#define CC   32
#define PP   64
#define PSTR 33   // LDS row stride: (33*j + 4*cg) % 32 gives <=2-way b128 conflicts (free)

__device__ __forceinline__ float4 f4min(float4 a, float4 b) {
    return make_float4(fminf(a.x,b.x), fminf(a.y,b.y), fminf(a.z,b.z), fminf(a.w,b.w));
}
__device__ __forceinline__ float4 f4max(float4 a, float4 b) {
    return make_float4(fmaxf(a.x,b.x), fmaxf(a.y,b.y), fmaxf(a.z,b.z), fmaxf(a.w,b.w));
}
__device__ __forceinline__ void f4add(float4& a, float4 v) {
    a.x += v.x; a.y += v.y; a.z += v.z; a.w += v.w;
}
__device__ __forceinline__ float4 shflxor4(float4 v, int m) {
    return make_float4(__shfl_xor(v.x, m), __shfl_xor(v.y, m),
                       __shfl_xor(v.z, m), __shfl_xor(v.w, m));
}

__global__ __launch_bounds__(1024, 4) void gaf_kernel(const float* __restrict__ x,
                                                      float* __restrict__ out) {
    __shared__ float sp[PP * PSTR];     // p[64][33]
    __shared__ float sy[PP * PSTR];     // y[64][33]
    __shared__ float redmin[16 * CC];
    __shared__ float redmax[16 * CC];

    const int tid  = threadIdx.x;
    const int lane = tid & 63;
    const int wave = tid >> 6;          // 0..15
    const int cg   = lane & 7;          // channel group [4cg, 4cg+4)
    const int b    = blockIdx.x;

    // ---- Phase 1: contiguous streaming, min/max + segment sums ----
    // Wave w: t in [w*256, w*256+256) = 32 KB contiguous = segments 4w..4w+3.
    // Chunk k (1 KB): t = w*256 + k*8 + (lane>>3), channels 4cg..4cg+3.
    const float4* xw = (const float4*)x + (size_t)b * (TT * CC / 4) + wave * 2048 + lane;

    const float FBIG = 3.402823466e+38f;
    float4 mn = make_float4(FBIG, FBIG, FBIG, FBIG);
    float4 mx = make_float4(-FBIG, -FBIG, -FBIG, -FBIG);
    float4 acc[4];
    #pragma unroll
    for (int g = 0; g < 4; ++g) acc[g] = make_float4(0.f, 0.f, 0.f, 0.f);

    #pragma unroll
    for (int g = 0; g < 4; ++g) {       // local segment g -> global segment 4*wave+g
        float4 buf[8];
        #pragma unroll
        for (int u = 0; u < 8; ++u) buf[u] = xw[(g * 8 + u) * 64];
        #pragma unroll
        for (int u = 0; u < 8; ++u) {
            mn = f4min(mn, buf[u]); mx = f4max(mx, buf[u]); f4add(acc[g], buf[u]);
        }
    }

    // reduce across the 8 t-offsets (lanes sharing cg are stride-8)
    #pragma unroll
    for (int m = 8; m <= 32; m <<= 1) {
        mn = f4min(mn, shflxor4(mn, m));
        mx = f4max(mx, shflxor4(mx, m));
        #pragma unroll
        for (int g = 0; g < 4; ++g) f4add(acc[g], shflxor4(acc[g], m));
    }

    if (lane < 8) {                     // lane == cg
        *(float4*)&redmin[wave * CC + cg * 4] = mn;
        *(float4*)&redmax[wave * CC + cg * 4] = mx;
    }
    __syncthreads();

    float4 gmn = *(const float4*)&redmin[0 * CC + cg * 4];
    float4 gmx = *(const float4*)&redmax[0 * CC + cg * 4];
    #pragma unroll
    for (int w = 1; w < 16; ++w) {
        gmn = f4min(gmn, *(const float4*)&redmin[w * CC + cg * 4]);
        gmx = f4max(gmx, *(const float4*)&redmax[w * CC + cg * 4]);
    }

    float4 inv;
    inv.x = 1.0f / (gmx.x - gmn.x);  inv.y = 1.0f / (gmx.y - gmn.y);
    inv.z = 1.0f / (gmx.z - gmn.z);  inv.w = 1.0f / (gmx.w - gmn.w);
    const float s64 = 1.0f / 64.0f;

    if (lane < 8) {
        #pragma unroll
        for (int g = 0; g < 4; ++g) {
            float4 p, y;
            p.x = (acc[g].x * s64 - gmn.x) * inv.x;  p.y = (acc[g].y * s64 - gmn.y) * inv.y;
            p.z = (acc[g].z * s64 - gmn.z) * inv.z;  p.w = (acc[g].w * s64 - gmn.w) * inv.w;
            y.x = sqrtf(fmaxf(1.f - p.x * p.x, 0.f));  y.y = sqrtf(fmaxf(1.f - p.y * p.y, 0.f));
            y.z = sqrtf(fmaxf(1.f - p.z * p.z, 0.f));  y.w = sqrtf(fmaxf(1.f - p.w * p.w, 0.f));
            const int s = wave * 4 + g;
            *(float4*)&sp[s * PSTR + cg * 4] = p;
            *(float4*)&sy[s * PSTR + cg * 4] = y;
        }
    }
    __syncthreads();

    // ---- Phase 2: out[b,i,j,c] = y_i*p_j - p_i*y_j ----
    // Wave w owns i in [4w, 4w+4) -> contiguous 32 KB, written sequentially.
    // Store chunk (ii,jc): lane l -> j = jc*8 + (l>>3), c-group = l&7.
    const int jrow = lane >> 3;
    float4 pj[8], yj[8];
    #pragma unroll
    for (int jc = 0; jc < 8; ++jc) {
        const int j = jc * 8 + jrow;
        pj[jc] = *(const float4*)&sp[j * PSTR + cg * 4];
        yj[jc] = *(const float4*)&sy[j * PSTR + cg * 4];
    }

    float4* ob = (float4*)out + (size_t)b * (PP * PP * CC / 4) + wave * 2048 + lane;

    #pragma unroll
    for (int ii = 0; ii < 4; ++ii) {
        const int i = wave * 4 + ii;
        const float4 pi = *(const float4*)&sp[i * PSTR + cg * 4];
        const float4 yi = *(const float4*)&sy[i * PSTR + cg * 4];
        #pragma unroll
        for (int jc = 0; jc < 8; ++jc) {
            float4 r;
            r.x = yi.x * pj[jc].x - pi.x * yj[jc].x;
            r.y = yi.y * pj[jc].y - pi.y * yj[jc].y;
            r.z = yi.z * pj[jc].z - pi.z * yj[jc].z;
            r.w = yi.w * pj[jc].w - pi.w * yj[jc].w;
            ob[ii * 512 + jc * 64] = r;
        }
    }
}

extern "C" void kernel_launch(void* const* d_in, const int* in_sizes, int n_in,
                              void* d_out, int out_size, void* d_ws, size_t ws_size,
                              hipStream_t stream) {
    const float* x = (const float*)d_in[0];
    float* out = (float*)d_out;
    gaf_kernel<<<BB, 1024, 0, stream>>>(x, out);
}